// Round 3
// baseline (1287.314 us; speedup 1.0000x reference)
//
#include <hip/hip_runtime.h>

typedef unsigned int uint;
typedef unsigned short ushort;

typedef __attribute__((ext_vector_type(8))) short sh8;
typedef __attribute__((ext_vector_type(4))) float f32x4;

__device__ __forceinline__ ushort f2b(float f) {
    uint x = __float_as_uint(f);
    x += 0x7fffu + ((x >> 16) & 1u);
    return (ushort)(x >> 16);
}
__device__ __forceinline__ float b2f(ushort u) {
    return __uint_as_float(((uint)u) << 16);
}
__device__ __forceinline__ uint pack2(float a, float b) {
    return (uint)f2b(a) | ((uint)f2b(b) << 16);
}
__device__ __forceinline__ float frcp(float x) { return __builtin_amdgcn_rcpf(x); }
// saturating via inf: exp(+inf)->inf -> rcp -> 0, no clamps needed
__device__ __forceinline__ float sigmf(float x) { return frcp(1.0f + __expf(-x)); }
__device__ __forceinline__ float tanhf2(float y) {
    return fmaf(2.0f, frcp(1.0f + __expf(-2.0f * y)), -1.0f);
}

// Relaxed barrier: drain LDS ops only (cross-wave LDS visibility), do NOT
// drain vmcnt — global prefetch loads/stores stay in flight across steps.
// __syncthreads() would emit s_waitcnt vmcnt(0) before s_barrier, serializing
// a full HBM round trip into every GRU step (the measured ~2300-cycle stall).
// Single opaque volatile asm with memory clobber: nothing is scheduled across.
__device__ __forceinline__ void barrier_lgkm() {
    asm volatile("s_waitcnt lgkmcnt(0)\n\ts_barrier" ::: "memory");
}

// ---------------------------------------------------------------------------
// Index-width detector for x (robustness; x believed int32).
// ---------------------------------------------------------------------------
__global__ __launch_bounds__(256) void k_detx(const uint* __restrict__ xw,
                                              int* __restrict__ flag) {
    __shared__ int sh[256];
    int t = threadIdx.x;
    int c = 0;
    for (int i = t; i < 2048; i += 256) c += (xw[2 * i + 1] == 0u) ? 1 : 0;
    sh[t] = c;
    __syncthreads();
    if (t == 0) {
        int s = 0;
        for (int i = 0; i < 256; i++) s += sh[i];
        flag[0] = (s >= 1843) ? 1 : 0;  // >=90% zeros -> int64
    }
}

// ---------------------------------------------------------------------------
// Embedding gather, fp32 -> bf16, index-width aware.
// ---------------------------------------------------------------------------
__global__ __launch_bounds__(256) void k_gather(const void* __restrict__ x,
                                                const float* __restrict__ embed,
                                                const int* __restrict__ flag,
                                                ushort* __restrict__ out) {
    int chunk = blockIdx.x * 256 + threadIdx.x;
    int row = chunk >> 5;
    int c = chunk & 31;
    int v;
    if (flag[0]) {
        v = (int)((const uint*)x)[2 * row];
    } else {
        v = ((const int*)x)[row];
    }
    v = min(max(v, 0), 49999);
    const float4* e = (const float4*)&embed[(size_t)v * 256 + (size_t)c * 8];
    float4 a = e[0], b = e[1];
    uint4 pv;
    pv.x = pack2(a.x, a.y);
    pv.y = pack2(a.z, a.w);
    pv.z = pack2(b.x, b.y);
    pv.w = pack2(b.z, b.w);
    *(uint4*)&out[(size_t)row * 256 + (size_t)c * 8] = pv;
}

// ---------------------------------------------------------------------------
// GEMM: C = A(bf16) * W^T(fp32 inline->bf16) + bias, optional GELU;
// bf16 Cb and/or fp32 Cf outputs. Barriers are lgkm-only: the global->reg
// loads are consumed by LDS writes via data deps (compiler waitcnts those),
// so the __syncthreads vmcnt(0) drain was pure overhead.
// ---------------------------------------------------------------------------
__global__ __launch_bounds__(256) void k_gemm_bt(const ushort* __restrict__ A,
                                                 const float* __restrict__ Wf,
                                                 const float* __restrict__ bias,
                                                 ushort* __restrict__ Cb,
                                                 float* __restrict__ Cf,
                                                 int M, int N, int K, int gelu) {
    __shared__ __align__(16) ushort Al[128 * 32];
    __shared__ __align__(16) ushort Bl[128 * 32];
    int tid = threadIdx.x;
    int bm = blockIdx.x, bn = blockIdx.y;
    int wid = tid >> 6, lane = tid & 63;
    int ln = lane & 15, kq = lane >> 4;
    int wm = (wid & 1) * 64, wn = (wid >> 1) * 64;
    int rowA0 = bm * 128, rowB0 = bn * 128;

    f32x4 acc[4][4];
#pragma unroll
    for (int i = 0; i < 4; i++)
#pragma unroll
        for (int j = 0; j < 4; j++) acc[i][j] = (f32x4){0.f, 0.f, 0.f, 0.f};

    for (int kt = 0; kt < K; kt += 32) {
#pragma unroll
        for (int c = tid; c < 512; c += 256) {
            int r = c >> 2, c8 = (c & 3) * 8;
            *(uint4*)&Al[r * 32 + c8] =
                *(const uint4*)&A[(size_t)(rowA0 + r) * K + kt + c8];
            int nb = rowB0 + r;
            uint4 bv = {0u, 0u, 0u, 0u};
            if (nb < N) {
                const float4* wp = (const float4*)&Wf[(size_t)nb * K + kt + c8];
                float4 w0 = wp[0], w1 = wp[1];
                bv.x = pack2(w0.x, w0.y);
                bv.y = pack2(w0.z, w0.w);
                bv.z = pack2(w1.x, w1.y);
                bv.w = pack2(w1.z, w1.w);
            }
            *(uint4*)&Bl[r * 32 + c8] = bv;
        }
        barrier_lgkm();
        sh8 af[4], bfr[4];
#pragma unroll
        for (int i = 0; i < 4; i++)
            af[i] = *(const sh8*)&Al[(wm + i * 16 + ln) * 32 + kq * 8];
#pragma unroll
        for (int j = 0; j < 4; j++)
            bfr[j] = *(const sh8*)&Bl[(wn + j * 16 + ln) * 32 + kq * 8];
#pragma unroll
        for (int i = 0; i < 4; i++)
#pragma unroll
            for (int j = 0; j < 4; j++)
                acc[i][j] = __builtin_amdgcn_mfma_f32_16x16x32_bf16(
                    af[i], bfr[j], acc[i][j], 0, 0, 0);
        barrier_lgkm();
    }

#pragma unroll
    for (int i = 0; i < 4; i++)
#pragma unroll
        for (int j = 0; j < 4; j++) {
            int col = rowB0 + wn + j * 16 + ln;
            if (col >= N) continue;
            float bv = bias[col];
#pragma unroll
            for (int reg = 0; reg < 4; reg++) {
                int row = rowA0 + wm + i * 16 + kq * 4 + reg;
                float v = acc[i][j][reg] + bv;
                if (gelu) v = 0.5f * v * (1.0f + erff(v * 0.70710678118f));
                if (Cb) Cb[(size_t)row * N + col] = f2b(v);
                if (Cf) Cf[(size_t)row * N + col] = v;
            }
        }
}

// ---------------------------------------------------------------------------
// GRU recurrence v4 — MFMA-batched, relaxed (lgkm-only) per-step barrier.
// grid = 8: dir = idx&1, b_base = (idx>>1)*16. 512 threads = 8 waves.
// Per step: hp[16b][384] = h[16b][128] @ Whh^T via 12 chained
// mfma_f32_16x16x32_bf16 per wave (wave w owns cols 16w..16w+16 of all
// three gates, so r/z/n accumulators land in-lane for the same (b,j)).
// Whh lives in VGPRs as bf16 B-fragments (loaded once). h double-buffers
// through LDS [16][136]. ONE lgkm-only barrier per step: global prefetch
// loads (xp, residual) and output stores stay in flight across barriers —
// the v3 profile showed __syncthreads' vmcnt(0) drain serialized a full
// memory round trip (~2300 cy) into every step. In-place hb hazard is
// resolved by data dependency: the store value depends on the prefetched
// load of the same address, and each (b,j,t) element is read/written by
// the same lane. fp32 hstate kept in registers for the z-blend.
// ---------------------------------------------------------------------------
struct PF {
    ushort xr[4], xz[4], xn[4], rv[4];
};

#define GRU_PREF(p, TS)                                                       \
    if ((TS) < 512) {                                                         \
        int tq_ = dir ? (511 - (TS)) : (TS);                                  \
        size_t xo_ = (size_t)tq_ * 768;                                       \
        size_t ho_ = (size_t)tq_ * 256;                                       \
        _Pragma("unroll") for (int r_ = 0; r_ < 4; r_++) {                    \
            const ushort* xq_ = xp + xb[r_] + xo_;                            \
            p.xr[r_] = xq_[0];                                                \
            p.xz[r_] = xq_[128];                                              \
            p.xn[r_] = xq_[256];                                              \
            p.rv[r_] = hb[hbase[r_] + ho_];                                   \
        }                                                                     \
    }

#define GRU_STEP(S, p)                                                        \
    {                                                                         \
        float xrf[4], xzf[4], xnf[4], rvf[4];                                 \
        _Pragma("unroll") for (int r_ = 0; r_ < 4; r_++) {                    \
            xrf[r_] = b2f(p.xr[r_]);                                          \
            xzf[r_] = b2f(p.xz[r_]);                                          \
            xnf[r_] = b2f(p.xn[r_]);                                          \
            rvf[r_] = b2f(p.rv[r_]);                                          \
        }                                                                     \
        GRU_PREF(p, (S) + 2);                                                 \
        const ushort* hrd = &hA[(S) & 1][ln][0];                              \
        sh8 a0 = *(const sh8*)&hrd[kq * 8];                                   \
        sh8 a1 = *(const sh8*)&hrd[32 + kq * 8];                              \
        sh8 a2 = *(const sh8*)&hrd[64 + kq * 8];                              \
        sh8 a3 = *(const sh8*)&hrd[96 + kq * 8];                              \
        f32x4 accr = (f32x4){0.f, 0.f, 0.f, 0.f};                             \
        f32x4 accz = accr, accn = accr;                                       \
        accr = __builtin_amdgcn_mfma_f32_16x16x32_bf16(a0, bfrag[0][0], accr, 0, 0, 0); \
        accz = __builtin_amdgcn_mfma_f32_16x16x32_bf16(a0, bfrag[1][0], accz, 0, 0, 0); \
        accn = __builtin_amdgcn_mfma_f32_16x16x32_bf16(a0, bfrag[2][0], accn, 0, 0, 0); \
        accr = __builtin_amdgcn_mfma_f32_16x16x32_bf16(a1, bfrag[0][1], accr, 0, 0, 0); \
        accz = __builtin_amdgcn_mfma_f32_16x16x32_bf16(a1, bfrag[1][1], accz, 0, 0, 0); \
        accn = __builtin_amdgcn_mfma_f32_16x16x32_bf16(a1, bfrag[2][1], accn, 0, 0, 0); \
        accr = __builtin_amdgcn_mfma_f32_16x16x32_bf16(a2, bfrag[0][2], accr, 0, 0, 0); \
        accz = __builtin_amdgcn_mfma_f32_16x16x32_bf16(a2, bfrag[1][2], accz, 0, 0, 0); \
        accn = __builtin_amdgcn_mfma_f32_16x16x32_bf16(a2, bfrag[2][2], accn, 0, 0, 0); \
        accr = __builtin_amdgcn_mfma_f32_16x16x32_bf16(a3, bfrag[0][3], accr, 0, 0, 0); \
        accz = __builtin_amdgcn_mfma_f32_16x16x32_bf16(a3, bfrag[1][3], accz, 0, 0, 0); \
        accn = __builtin_amdgcn_mfma_f32_16x16x32_bf16(a3, bfrag[2][3], accn, 0, 0, 0); \
        int tw_ = dir ? (511 - (S)) : (S);                                    \
        size_t hw_ = (size_t)tw_ * 256;                                       \
        ushort* hwr = &hA[1 - ((S) & 1)][0][0];                               \
        _Pragma("unroll") for (int r_ = 0; r_ < 4; r_++) {                    \
            float rg = sigmf(xrf[r_] + accr[r_] + bh_r);                      \
            float zg = sigmf(xzf[r_] + accz[r_] + bh_z);                      \
            float ng = tanhf2(fmaf(rg, accn[r_] + bh_n, xnf[r_]));            \
            float h = fmaf(zg, hstate[r_] - ng, ng);                          \
            hstate[r_] = h;                                                   \
            hwr[(kq * 4 + r_) * 136 + jcol] = f2b(h);                         \
            hb[hbase[r_] + hw_] = f2b(h + rvf[r_]);                           \
        }                                                                     \
        barrier_lgkm();                                                       \
    }

__global__ __launch_bounds__(512, 1) void k_gru(const ushort* __restrict__ xp,
                                                const float* __restrict__ Whh_l,
                                                const float* __restrict__ bhh_l,
                                                ushort* __restrict__ hb) {
    __shared__ __align__(16) ushort hA[2][16][136];

    const int t = threadIdx.x;
    const int w = t >> 6, l = t & 63;
    const int ln = l & 15, kq = l >> 4;
    const int jcol = (w << 4) + ln;  // hidden column this lane's C-tile covers
    const int dir = blockIdx.x & 1;
    const int b_base = (blockIdx.x >> 1) << 4;

    const float* Wd = Whh_l + (size_t)dir * 384 * 128;
    const float* bhh_d = bhh_l + dir * 384;

    // Whh B-fragments, bf16, resident in VGPRs for all 512 steps.
    // B-frag layout: lane holds W[row = tilebase + (lane&15)][k = (lane>>4)*8 .. +8]
    sh8 bfrag[3][4];
#pragma unroll
    for (int g = 0; g < 3; g++)
#pragma unroll
        for (int kt = 0; kt < 4; kt++) {
            const float4* wp =
                (const float4*)(Wd + (size_t)(g * 128 + jcol) * 128 + kt * 32 + kq * 8);
            float4 w0 = wp[0], w1 = wp[1];
            uint4 pv;
            pv.x = pack2(w0.x, w0.y);
            pv.y = pack2(w0.z, w0.w);
            pv.z = pack2(w1.x, w1.y);
            pv.w = pack2(w1.z, w1.w);
            bfrag[g][kt] = *(sh8*)&pv;
        }

    const float bh_r = bhh_d[jcol];
    const float bh_z = bhh_d[128 + jcol];
    const float bh_n = bhh_d[256 + jcol];

    // Per-reg global address bases (C row b = kq*4 + reg).
    size_t xb[4], hbase[4];
#pragma unroll
    for (int r = 0; r < 4; r++) {
        size_t rb = (size_t)(b_base + kq * 4 + r) * 512;
        xb[r] = rb * 768 + (size_t)dir * 384 + jcol;
        hbase[r] = rb * 256 + (size_t)dir * 128 + jcol;
    }

    float hstate[4] = {0.f, 0.f, 0.f, 0.f};

    // h0 = 0
    for (int i = t; i < 16 * 136; i += 512) ((ushort*)hA[0])[i] = 0;

    PF pA, pB;
    GRU_PREF(pA, 0);
    GRU_PREF(pB, 1);
    __syncthreads();  // once; full drain is fine here

    for (int s = 0; s < 512; s += 2) {
        GRU_STEP(s, pA)
        GRU_STEP(s + 1, pB)
    }
}

// ---------------------------------------------------------------------------
// Host launcher. fp32 inputs AND fp32 output; bf16 internally for MFMA.
// Scratch confined to 64 MiB:
//   [0, 48M)  xp (bf16 32768x768) — also hosts embA, then g (16 MiB each)
//   [48,64M)  hb (bf16 32768x256) — W1 out, GRU layers update in place
// ---------------------------------------------------------------------------
extern "C" void kernel_launch(void* const* d_in, const int* in_sizes, int n_in,
                              void* d_out, int out_size, void* d_ws, size_t ws_size,
                              hipStream_t stream) {
    const void* x = d_in[0];
    const float* embed = (const float*)d_in[1];
    const float* W1 = (const float*)d_in[2];
    const float* b1 = (const float*)d_in[3];
    const float* Wih = (const float*)d_in[4];  // [2][2][384][256]
    const float* Whh = (const float*)d_in[5];  // [2][2][384][128]
    const float* bih = (const float*)d_in[6];  // [2][2][384]
    const float* bhh = (const float*)d_in[7];  // [2][2][384]
    const float* W2 = (const float*)d_in[8];
    const float* b2 = (const float*)d_in[9];
    const float* W3 = (const float*)d_in[10];
    const float* b3 = (const float*)d_in[11];

    char* ws = (char*)d_ws;
    ushort* xp = (ushort*)ws;                         // [0, 48M)
    ushort* hb = (ushort*)(ws + 32768ull * 768 * 2);  // [48M, 64M)
    ushort* embA = xp;  // 16 MiB slot, dead after W1 GEMM
    ushort* g = xp;     // reused after last GRU
    int* xflag = (int*)hb;  // transient; dead after k_gather

    // detect x index width, then gather + W1: hb = bf16(embA @ W1^T + b1)
    k_detx<<<1, 256, 0, stream>>>((const uint*)x, xflag);
    k_gather<<<4096, 256, 0, stream>>>(x, embed, xflag, embA);
    k_gemm_bt<<<dim3(256, 2), 256, 0, stream>>>(embA, W1, b1, hb, (float*)0,
                                                32768, 256, 256, 0);

    // layer 0: xp = hb @ Wih[0]^T + bih[0]; GRU updates hb in place
    k_gemm_bt<<<dim3(256, 6), 256, 0, stream>>>(hb, Wih, bih, xp, (float*)0,
                                                32768, 768, 256, 0);
    k_gru<<<8, 512, 0, stream>>>(xp, Whh, bhh, hb);

    // layer 1
    k_gemm_bt<<<dim3(256, 6), 256, 0, stream>>>(hb, Wih + 196608, bih + 768,
                                                xp, (float*)0, 32768, 768, 256, 0);
    k_gru<<<8, 512, 0, stream>>>(xp, Whh + 98304, bhh + 768, hb);

    // head: g = bf16(GELU(hb @ W2^T + b2)); d_out = fp32(g @ W3^T + b3)
    k_gemm_bt<<<dim3(256, 2), 256, 0, stream>>>(hb, W2, b2, g, (float*)0,
                                                32768, 256, 256, 1);
    k_gemm_bt<<<dim3(256, 1), 256, 0, stream>>>(g, W3, b3, (ushort*)0,
                                                (float*)d_out, 32768, 50, 256, 0);
}

// Round 4
// 1246.161 us; speedup vs baseline: 1.0330x; 1.0330x over previous
//
#include <hip/hip_runtime.h>

typedef unsigned int uint;
typedef unsigned short ushort;

typedef __attribute__((ext_vector_type(8))) short sh8;
typedef __attribute__((ext_vector_type(4))) float f32x4;

__device__ __forceinline__ ushort f2b(float f) {
    uint x = __float_as_uint(f);
    x += 0x7fffu + ((x >> 16) & 1u);
    return (ushort)(x >> 16);
}
__device__ __forceinline__ float b2f(ushort u) {
    return __uint_as_float(((uint)u) << 16);
}
__device__ __forceinline__ uint pack2(float a, float b) {
    return (uint)f2b(a) | ((uint)f2b(b) << 16);
}
// RTNE pack of two f32 -> two bf16 in one instruction (guide T12 pattern).
__device__ __forceinline__ uint cvt_pk_bf16(float lo, float hi) {
    uint r;
    asm("v_cvt_pk_bf16_f32 %0, %1, %2" : "=v"(r) : "v"(lo), "v"(hi));
    return r;
}
__device__ __forceinline__ float frcp(float x) { return __builtin_amdgcn_rcpf(x); }
__device__ __forceinline__ float sigmf(float x) { return frcp(1.0f + __expf(-x)); }
__device__ __forceinline__ float tanhf2(float y) {
    return fmaf(2.0f, frcp(1.0f + __expf(-2.0f * y)), -1.0f);
}

// Relaxed barrier: drain LDS ops only; global loads/stores stay in flight.
__device__ __forceinline__ void barrier_lgkm() {
    asm volatile("s_waitcnt lgkmcnt(0)\n\ts_barrier" ::: "memory");
}

// ---------------------------------------------------------------------------
// Index-width detector for x (robustness; x believed int32).
// ---------------------------------------------------------------------------
__global__ __launch_bounds__(256) void k_detx(const uint* __restrict__ xw,
                                              int* __restrict__ flag) {
    __shared__ int sh[256];
    int t = threadIdx.x;
    int c = 0;
    for (int i = t; i < 2048; i += 256) c += (xw[2 * i + 1] == 0u) ? 1 : 0;
    sh[t] = c;
    __syncthreads();
    if (t == 0) {
        int s = 0;
        for (int i = 0; i < 256; i++) s += sh[i];
        flag[0] = (s >= 1843) ? 1 : 0;  // >=90% zeros -> int64
    }
}

// ---------------------------------------------------------------------------
// Embedding gather, fp32 -> bf16, index-width aware.
// ---------------------------------------------------------------------------
__global__ __launch_bounds__(256) void k_gather(const void* __restrict__ x,
                                                const float* __restrict__ embed,
                                                const int* __restrict__ flag,
                                                ushort* __restrict__ out) {
    int chunk = blockIdx.x * 256 + threadIdx.x;
    int row = chunk >> 5;
    int c = chunk & 31;
    int v;
    if (flag[0]) {
        v = (int)((const uint*)x)[2 * row];
    } else {
        v = ((const int*)x)[row];
    }
    v = min(max(v, 0), 49999);
    const float4* e = (const float4*)&embed[(size_t)v * 256 + (size_t)c * 8];
    float4 a = e[0], b = e[1];
    uint4 pv;
    pv.x = pack2(a.x, a.y);
    pv.y = pack2(a.z, a.w);
    pv.z = pack2(b.x, b.y);
    pv.w = pack2(b.z, b.w);
    *(uint4*)&out[(size_t)row * 256 + (size_t)c * 8] = pv;
}

// ---------------------------------------------------------------------------
// GEMM (verified): C = A(bf16) * W^T(fp32 inline->bf16) + bias, optional
// GELU; bf16 Cb and/or fp32 Cf outputs. lgkm-only barriers.
// ---------------------------------------------------------------------------
__global__ __launch_bounds__(256) void k_gemm_bt(const ushort* __restrict__ A,
                                                 const float* __restrict__ Wf,
                                                 const float* __restrict__ bias,
                                                 ushort* __restrict__ Cb,
                                                 float* __restrict__ Cf,
                                                 int M, int N, int K, int gelu) {
    __shared__ __align__(16) ushort Al[128 * 32];
    __shared__ __align__(16) ushort Bl[128 * 32];
    int tid = threadIdx.x;
    int bm = blockIdx.x, bn = blockIdx.y;
    int wid = tid >> 6, lane = tid & 63;
    int ln = lane & 15, kq = lane >> 4;
    int wm = (wid & 1) * 64, wn = (wid >> 1) * 64;
    int rowA0 = bm * 128, rowB0 = bn * 128;

    f32x4 acc[4][4];
#pragma unroll
    for (int i = 0; i < 4; i++)
#pragma unroll
        for (int j = 0; j < 4; j++) acc[i][j] = (f32x4){0.f, 0.f, 0.f, 0.f};

    for (int kt = 0; kt < K; kt += 32) {
#pragma unroll
        for (int c = tid; c < 512; c += 256) {
            int r = c >> 2, c8 = (c & 3) * 8;
            *(uint4*)&Al[r * 32 + c8] =
                *(const uint4*)&A[(size_t)(rowA0 + r) * K + kt + c8];
            int nb = rowB0 + r;
            uint4 bv = {0u, 0u, 0u, 0u};
            if (nb < N) {
                const float4* wp = (const float4*)&Wf[(size_t)nb * K + kt + c8];
                float4 w0 = wp[0], w1 = wp[1];
                bv.x = pack2(w0.x, w0.y);
                bv.y = pack2(w0.z, w0.w);
                bv.z = pack2(w1.x, w1.y);
                bv.w = pack2(w1.z, w1.w);
            }
            *(uint4*)&Bl[r * 32 + c8] = bv;
        }
        barrier_lgkm();
        sh8 af[4], bfr[4];
#pragma unroll
        for (int i = 0; i < 4; i++)
            af[i] = *(const sh8*)&Al[(wm + i * 16 + ln) * 32 + kq * 8];
#pragma unroll
        for (int j = 0; j < 4; j++)
            bfr[j] = *(const sh8*)&Bl[(wn + j * 16 + ln) * 32 + kq * 8];
#pragma unroll
        for (int i = 0; i < 4; i++)
#pragma unroll
            for (int j = 0; j < 4; j++)
                acc[i][j] = __builtin_amdgcn_mfma_f32_16x16x32_bf16(
                    af[i], bfr[j], acc[i][j], 0, 0, 0);
        barrier_lgkm();
    }

#pragma unroll
    for (int i = 0; i < 4; i++)
#pragma unroll
        for (int j = 0; j < 4; j++) {
            int col = rowB0 + wn + j * 16 + ln;
            if (col >= N) continue;
            float bv = bias[col];
#pragma unroll
            for (int reg = 0; reg < 4; reg++) {
                int row = rowA0 + wm + i * 16 + kq * 4 + reg;
                float v = acc[i][j][reg] + bv;
                if (gelu) v = 0.5f * v * (1.0f + erff(v * 0.70710678118f));
                if (Cb) Cb[(size_t)row * N + col] = f2b(v);
                if (Cf) Cf[(size_t)row * N + col] = v;
            }
        }
}

// ---------------------------------------------------------------------------
// GRU recurrence v5 — MFMA-batched, VALU-lean addressing.
// Same verified structure as v3/v4 (12 MFMA/step/wave, LDS h double-buffer,
// 2-step prefetch, in-place hb). Changes vs v4, all VALU-overhead cuts:
//  * direction sign DS is a template parameter -> all per-step address
//    deltas are compile-time; loads/stores use saddr + 32-bit running int
//    offsets + 13-bit immediates (3072/3584/1024 bytes, within +-4096).
//    8 v_add per step replaces the per-step 64-bit mul/add chains.
//  * v_cvt_pk_bf16_f32 (RTNE, same as f2b) packs h pairs: 4 cvt_pk + 4
//    lshr replaces 8 five-op f2b sequences.
//  * LDS read/write base pointers hoisted per unroll-parity (imm offsets).
// Theory: per-active-CU VALUBusy ~64% -> step time is VALU-issue-bound on
// overhead, not on gate math or MFMA.
// ---------------------------------------------------------------------------
struct PF {
    ushort xr[4], xz[4], xn[4], rv[4];
};

template <int DS>  // +1 forward, -1 backward
__device__ __forceinline__ void gru_impl(const ushort* __restrict__ xp,
                                         const float* __restrict__ Whh_l,
                                         const float* __restrict__ bhh_l,
                                         ushort* __restrict__ hb,
                                         int dir, int b_base, int t,
                                         ushort* lds) {
    constexpr int XS = DS * 1536;  // xp row stride per time step, bytes
    constexpr int HS = DS * 512;   // hb row stride per time step, bytes
    const int w = t >> 6, l = t & 63;
    const int ln = l & 15, kq = l >> 4;
    const int jcol = (w << 4) + ln;

    const float* Wd = Whh_l + (size_t)dir * 384 * 128;
    const float* bhh_d = bhh_l + dir * 384;

    // Whh B-fragments, bf16, resident in VGPRs (cold path, size_t fine).
    sh8 bfrag[3][4];
#pragma unroll
    for (int g = 0; g < 3; g++)
#pragma unroll
        for (int kt = 0; kt < 4; kt++) {
            const float4* wp =
                (const float4*)(Wd + (size_t)(g * 128 + jcol) * 128 + kt * 32 + kq * 8);
            float4 w0 = wp[0], w1 = wp[1];
            uint4 pv;
            pv.x = pack2(w0.x, w0.y);
            pv.y = pack2(w0.z, w0.w);
            pv.z = pack2(w1.x, w1.y);
            pv.w = pack2(w1.z, w1.w);
            bfrag[g][kt] = *(sh8*)&pv;
        }

    const float bh_r = bhh_d[jcol];
    const float bh_z = bhh_d[128 + jcol];
    const float bh_n = bhh_d[256 + jcol];

    // Running byte offsets at the CURRENT step's time index (store target).
    const char* xpb = (const char*)xp;
    char* hbb = (char*)hb;
    const int t0 = (DS > 0) ? 0 : 511;
    int xo[4], ho[4];
#pragma unroll
    for (int r = 0; r < 4; r++) {
        int row = (b_base + kq * 4 + r) * 512 + t0;
        xo[r] = row * 1536 + (dir * 384 + jcol) * 2;
        ho[r] = row * 512 + (dir * 128 + jcol) * 2;
    }

    float hstate[4] = {0.f, 0.f, 0.f, 0.f};

    // h0 = 0 in buffer 0
    for (int i = t; i < 16 * 136; i += 512) lds[i] = 0;

#define PREF(p, D)                                                            \
    _Pragma("unroll") for (int r_ = 0; r_ < 4; r_++) {                        \
        p.xr[r_] = *(const ushort*)(xpb + xo[r_] + (D) * XS);                 \
        p.xz[r_] = *(const ushort*)(xpb + xo[r_] + (D) * XS + 256);           \
        p.xn[r_] = *(const ushort*)(xpb + xo[r_] + (D) * XS + 512);           \
        p.rv[r_] = *(const ushort*)(hbb + ho[r_] + (D) * HS);                 \
    }

    PF pA, pB;
    PREF(pA, 0)
    PREF(pB, 1)
    __syncthreads();

#define GSTEP(PAR, p, guard)                                                  \
    {                                                                         \
        float xrf[4], xzf[4], xnf[4], rvf[4];                                 \
        _Pragma("unroll") for (int r_ = 0; r_ < 4; r_++) {                    \
            xrf[r_] = b2f(p.xr[r_]);                                          \
            xzf[r_] = b2f(p.xz[r_]);                                          \
            xnf[r_] = b2f(p.xn[r_]);                                          \
            rvf[r_] = b2f(p.rv[r_]);                                          \
        }                                                                     \
        if (guard) { PREF(p, 2) }                                             \
        const ushort* hrd = lds + (PAR)*2176 + ln * 136 + kq * 8;             \
        sh8 a0 = *(const sh8*)(hrd);                                          \
        sh8 a1 = *(const sh8*)(hrd + 32);                                     \
        sh8 a2 = *(const sh8*)(hrd + 64);                                     \
        sh8 a3 = *(const sh8*)(hrd + 96);                                     \
        f32x4 accr = (f32x4){0.f, 0.f, 0.f, 0.f};                             \
        f32x4 accz = accr, accn = accr;                                       \
        accr = __builtin_amdgcn_mfma_f32_16x16x32_bf16(a0, bfrag[0][0], accr, 0, 0, 0); \
        accz = __builtin_amdgcn_mfma_f32_16x16x32_bf16(a0, bfrag[1][0], accz, 0, 0, 0); \
        accn = __builtin_amdgcn_mfma_f32_16x16x32_bf16(a0, bfrag[2][0], accn, 0, 0, 0); \
        accr = __builtin_amdgcn_mfma_f32_16x16x32_bf16(a1, bfrag[0][1], accr, 0, 0, 0); \
        accz = __builtin_amdgcn_mfma_f32_16x16x32_bf16(a1, bfrag[1][1], accz, 0, 0, 0); \
        accn = __builtin_amdgcn_mfma_f32_16x16x32_bf16(a1, bfrag[2][1], accn, 0, 0, 0); \
        accr = __builtin_amdgcn_mfma_f32_16x16x32_bf16(a2, bfrag[0][2], accr, 0, 0, 0); \
        accz = __builtin_amdgcn_mfma_f32_16x16x32_bf16(a2, bfrag[1][2], accz, 0, 0, 0); \
        accn = __builtin_amdgcn_mfma_f32_16x16x32_bf16(a2, bfrag[2][2], accn, 0, 0, 0); \
        accr = __builtin_amdgcn_mfma_f32_16x16x32_bf16(a3, bfrag[0][3], accr, 0, 0, 0); \
        accz = __builtin_amdgcn_mfma_f32_16x16x32_bf16(a3, bfrag[1][3], accz, 0, 0, 0); \
        accn = __builtin_amdgcn_mfma_f32_16x16x32_bf16(a3, bfrag[2][3], accn, 0, 0, 0); \
        float hv[4], sv[4];                                                   \
        _Pragma("unroll") for (int r_ = 0; r_ < 4; r_++) {                    \
            float rg = sigmf(xrf[r_] + accr[r_] + bh_r);                      \
            float zg = sigmf(xzf[r_] + accz[r_] + bh_z);                      \
            float ng = tanhf2(fmaf(rg, accn[r_] + bh_n, xnf[r_]));            \
            float h = fmaf(zg, hstate[r_] - ng, ng);                          \
            hstate[r_] = h;                                                   \
            hv[r_] = h;                                                       \
            sv[r_] = h + rvf[r_];                                             \
        }                                                                     \
        uint u01 = cvt_pk_bf16(hv[0], hv[1]);                                 \
        uint u23 = cvt_pk_bf16(hv[2], hv[3]);                                 \
        ushort* hw = lds + (1 - (PAR)) * 2176 + (kq * 4) * 136 + jcol;        \
        hw[0] = (ushort)u01;                                                  \
        hw[136] = (ushort)(u01 >> 16);                                        \
        hw[272] = (ushort)u23;                                                \
        hw[408] = (ushort)(u23 >> 16);                                        \
        uint s01 = cvt_pk_bf16(sv[0], sv[1]);                                 \
        uint s23 = cvt_pk_bf16(sv[2], sv[3]);                                 \
        *(ushort*)(hbb + ho[0]) = (ushort)s01;                                \
        *(ushort*)(hbb + ho[1]) = (ushort)(s01 >> 16);                        \
        *(ushort*)(hbb + ho[2]) = (ushort)s23;                                \
        *(ushort*)(hbb + ho[3]) = (ushort)(s23 >> 16);                        \
        _Pragma("unroll") for (int r_ = 0; r_ < 4; r_++) {                    \
            xo[r_] += XS;                                                     \
            ho[r_] += HS;                                                     \
        }                                                                     \
        barrier_lgkm();                                                       \
    }

    for (int s = 0; s < 512; s += 2) {
        GSTEP(0, pA, (s + 2 < 512))
        GSTEP(1, pB, (s + 3 < 512))
    }
#undef PREF
#undef GSTEP
}

__global__ __launch_bounds__(512, 1) void k_gru(const ushort* __restrict__ xp,
                                                const float* __restrict__ Whh_l,
                                                const float* __restrict__ bhh_l,
                                                ushort* __restrict__ hb) {
    __shared__ __align__(16) ushort lds[2 * 16 * 136];
    const int dir = blockIdx.x & 1;
    const int b_base = (blockIdx.x >> 1) << 4;
    if (dir == 0)
        gru_impl<1>(xp, Whh_l, bhh_l, hb, dir, b_base, threadIdx.x, lds);
    else
        gru_impl<-1>(xp, Whh_l, bhh_l, hb, dir, b_base, threadIdx.x, lds);
}

// ---------------------------------------------------------------------------
// Host launcher. fp32 inputs AND fp32 output; bf16 internally for MFMA.
// Scratch confined to 64 MiB:
//   [0, 48M)  xp (bf16 32768x768) — also hosts embA, then g (16 MiB each)
//   [48,64M)  hb (bf16 32768x256) — W1 out, GRU layers update in place
// ---------------------------------------------------------------------------
extern "C" void kernel_launch(void* const* d_in, const int* in_sizes, int n_in,
                              void* d_out, int out_size, void* d_ws, size_t ws_size,
                              hipStream_t stream) {
    const void* x = d_in[0];
    const float* embed = (const float*)d_in[1];
    const float* W1 = (const float*)d_in[2];
    const float* b1 = (const float*)d_in[3];
    const float* Wih = (const float*)d_in[4];  // [2][2][384][256]
    const float* Whh = (const float*)d_in[5];  // [2][2][384][128]
    const float* bih = (const float*)d_in[6];  // [2][2][384]
    const float* bhh = (const float*)d_in[7];  // [2][2][384]
    const float* W2 = (const float*)d_in[8];
    const float* b2 = (const float*)d_in[9];
    const float* W3 = (const float*)d_in[10];
    const float* b3 = (const float*)d_in[11];

    char* ws = (char*)d_ws;
    ushort* xp = (ushort*)ws;                         // [0, 48M)
    ushort* hb = (ushort*)(ws + 32768ull * 768 * 2);  // [48M, 64M)
    ushort* embA = xp;  // 16 MiB slot, dead after W1 GEMM
    ushort* g = xp;     // reused after last GRU
    int* xflag = (int*)hb;  // transient; dead after k_gather

    // detect x index width, then gather + W1: hb = bf16(embA @ W1^T + b1)
    k_detx<<<1, 256, 0, stream>>>((const uint*)x, xflag);
    k_gather<<<4096, 256, 0, stream>>>(x, embed, xflag, embA);
    k_gemm_bt<<<dim3(256, 2), 256, 0, stream>>>(embA, W1, b1, hb, (float*)0,
                                                32768, 256, 256, 0);

    // layer 0: xp = hb @ Wih[0]^T + bih[0]; GRU updates hb in place
    k_gemm_bt<<<dim3(256, 6), 256, 0, stream>>>(hb, Wih, bih, xp, (float*)0,
                                                32768, 768, 256, 0);
    k_gru<<<8, 512, 0, stream>>>(xp, Whh, bhh, hb);

    // layer 1
    k_gemm_bt<<<dim3(256, 6), 256, 0, stream>>>(hb, Wih + 196608, bih + 768,
                                                xp, (float*)0, 32768, 768, 256, 0);
    k_gru<<<8, 512, 0, stream>>>(xp, Whh + 98304, bhh + 768, hb);

    // head: g = bf16(GELU(hb @ W2^T + b2)); d_out = fp32(g @ W3^T + b3)
    k_gemm_bt<<<dim3(256, 2), 256, 0, stream>>>(hb, W2, b2, g, (float*)0,
                                                32768, 256, 256, 1);
    k_gemm_bt<<<dim3(256, 1), 256, 0, stream>>>(g, W3, b3, (ushort*)0,
                                                (float*)d_out, 32768, 50, 256, 0);
}

// Round 5
// 1089.817 us; speedup vs baseline: 1.1812x; 1.1435x over previous
//
#include <hip/hip_runtime.h>

typedef unsigned int uint;
typedef unsigned short ushort;

typedef __attribute__((ext_vector_type(8))) short sh8;
typedef __attribute__((ext_vector_type(4))) float f32x4;

__device__ __forceinline__ ushort f2b(float f) {
    uint x = __float_as_uint(f);
    x += 0x7fffu + ((x >> 16) & 1u);
    return (ushort)(x >> 16);
}
__device__ __forceinline__ float b2f(ushort u) {
    return __uint_as_float(((uint)u) << 16);
}
__device__ __forceinline__ uint pack2(float a, float b) {
    return (uint)f2b(a) | ((uint)f2b(b) << 16);
}
// RTNE pack of two f32 -> two bf16 in one instruction.
__device__ __forceinline__ uint cvt_pk_bf16(float lo, float hi) {
    uint r;
    asm("v_cvt_pk_bf16_f32 %0, %1, %2" : "=v"(r) : "v"(lo), "v"(hi));
    return r;
}
__device__ __forceinline__ float frcp(float x) { return __builtin_amdgcn_rcpf(x); }
__device__ __forceinline__ float sigmf(float x) { return frcp(1.0f + __expf(-x)); }
__device__ __forceinline__ float tanhf2(float y) {
    return fmaf(2.0f, frcp(1.0f + __expf(-2.0f * y)), -1.0f);
}

// ---------------------------------------------------------------------------
// Index-width detector for x (robustness; x believed int32).
// ---------------------------------------------------------------------------
__global__ __launch_bounds__(256) void k_detx(const uint* __restrict__ xw,
                                              int* __restrict__ flag) {
    __shared__ int sh[256];
    int t = threadIdx.x;
    int c = 0;
    for (int i = t; i < 2048; i += 256) c += (xw[2 * i + 1] == 0u) ? 1 : 0;
    sh[t] = c;
    __syncthreads();
    if (t == 0) {
        int s = 0;
        for (int i = 0; i < 256; i++) s += sh[i];
        flag[0] = (s >= 1843) ? 1 : 0;  // >=90% zeros -> int64
    }
}

// ---------------------------------------------------------------------------
// Embedding gather, fp32 -> bf16, index-width aware.
// ---------------------------------------------------------------------------
__global__ __launch_bounds__(256) void k_gather(const void* __restrict__ x,
                                                const float* __restrict__ embed,
                                                const int* __restrict__ flag,
                                                ushort* __restrict__ out) {
    int chunk = blockIdx.x * 256 + threadIdx.x;
    int row = chunk >> 5;
    int c = chunk & 31;
    int v;
    if (flag[0]) {
        v = (int)((const uint*)x)[2 * row];
    } else {
        v = ((const int*)x)[row];
    }
    v = min(max(v, 0), 49999);
    const float4* e = (const float4*)&embed[(size_t)v * 256 + (size_t)c * 8];
    float4 a = e[0], b = e[1];
    uint4 pv;
    pv.x = pack2(a.x, a.y);
    pv.y = pack2(a.z, a.w);
    pv.z = pack2(b.x, b.y);
    pv.w = pack2(b.z, b.w);
    *(uint4*)&out[(size_t)row * 256 + (size_t)c * 8] = pv;
}

// ---------------------------------------------------------------------------
// GEMM (verified at baseline): C = A(bf16) * W^T(fp32 inline->bf16) + bias,
// optional GELU; bf16 Cb and/or fp32 Cf outputs. Plain __syncthreads.
// ---------------------------------------------------------------------------
__global__ __launch_bounds__(256) void k_gemm_bt(const ushort* __restrict__ A,
                                                 const float* __restrict__ Wf,
                                                 const float* __restrict__ bias,
                                                 ushort* __restrict__ Cb,
                                                 float* __restrict__ Cf,
                                                 int M, int N, int K, int gelu) {
    __shared__ __align__(16) ushort Al[128 * 32];
    __shared__ __align__(16) ushort Bl[128 * 32];
    int tid = threadIdx.x;
    int bm = blockIdx.x, bn = blockIdx.y;
    int wid = tid >> 6, lane = tid & 63;
    int ln = lane & 15, kq = lane >> 4;
    int wm = (wid & 1) * 64, wn = (wid >> 1) * 64;
    int rowA0 = bm * 128, rowB0 = bn * 128;

    f32x4 acc[4][4];
#pragma unroll
    for (int i = 0; i < 4; i++)
#pragma unroll
        for (int j = 0; j < 4; j++) acc[i][j] = (f32x4){0.f, 0.f, 0.f, 0.f};

    for (int kt = 0; kt < K; kt += 32) {
#pragma unroll
        for (int c = tid; c < 512; c += 256) {
            int r = c >> 2, c8 = (c & 3) * 8;
            *(uint4*)&Al[r * 32 + c8] =
                *(const uint4*)&A[(size_t)(rowA0 + r) * K + kt + c8];
            int nb = rowB0 + r;
            uint4 bv = {0u, 0u, 0u, 0u};
            if (nb < N) {
                const float4* wp = (const float4*)&Wf[(size_t)nb * K + kt + c8];
                float4 w0 = wp[0], w1 = wp[1];
                bv.x = pack2(w0.x, w0.y);
                bv.y = pack2(w0.z, w0.w);
                bv.z = pack2(w1.x, w1.y);
                bv.w = pack2(w1.z, w1.w);
            }
            *(uint4*)&Bl[r * 32 + c8] = bv;
        }
        __syncthreads();
        sh8 af[4], bfr[4];
#pragma unroll
        for (int i = 0; i < 4; i++)
            af[i] = *(const sh8*)&Al[(wm + i * 16 + ln) * 32 + kq * 8];
#pragma unroll
        for (int j = 0; j < 4; j++)
            bfr[j] = *(const sh8*)&Bl[(wn + j * 16 + ln) * 32 + kq * 8];
#pragma unroll
        for (int i = 0; i < 4; i++)
#pragma unroll
            for (int j = 0; j < 4; j++)
                acc[i][j] = __builtin_amdgcn_mfma_f32_16x16x32_bf16(
                    af[i], bfr[j], acc[i][j], 0, 0, 0);
        __syncthreads();
    }

#pragma unroll
    for (int i = 0; i < 4; i++)
#pragma unroll
        for (int j = 0; j < 4; j++) {
            int col = rowB0 + wn + j * 16 + ln;
            if (col >= N) continue;
            float bv = bias[col];
#pragma unroll
            for (int reg = 0; reg < 4; reg++) {
                int row = rowA0 + wm + i * 16 + kq * 4 + reg;
                float v = acc[i][j][reg] + bv;
                if (gelu) v = 0.5f * v * (1.0f + erff(v * 0.70710678118f));
                if (Cb) Cb[(size_t)row * N + col] = f2b(v);
                if (Cf) Cf[(size_t)row * N + col] = v;
            }
        }
}

// ---------------------------------------------------------------------------
// GRU recurrence v6 — manual vmem stream with COUNTED vmcnt (T3/T4).
// Same verified compute structure as v3-v5 (12 MFMA/step/wave, LDS h
// double-buffer, distance-2 register prefetch, in-place hb). New: ALL
// per-step global ops are inline asm (global_load_ushort /
// global_store_short, SGPR base + 32-bit voffset + imm offset), so the
// compiler has no vmem to wait on in the loop; consumption is gated by
// counted s_waitcnt vmcnt(N) — never 0. Per step: 16 loads + 4 stores.
// Steady state wait = 4(stores S-2) + 16+4(S-1) = vmcnt(24). Peeled
// first pair (16, 20) and last pair (24, 8; tail skips prefetch).
// Barrier = bare-asm lgkmcnt(0) + builtin s_barrier + sched_barrier(0)
// fences (the proven m201/m218 pattern — no "memory" clobber, which is
// suspected of triggering a conservative per-step vmcnt drain in v4/v5).
// ---------------------------------------------------------------------------
struct PF {
    uint xr[4], xz[4], xn[4], rv[4];
};

#define GLOAD(dst, off, base, IMM)                                            \
    asm volatile("global_load_ushort %0, %1, %2 offset:" IMM                  \
                 : "=v"(dst)                                                  \
                 : "v"(off), "s"(base))

#define GSTORE(off, data, base)                                               \
    asm volatile("global_store_short %0, %1, %2" ::"v"(off), "v"(data),       \
                 "s"(base))

// Loads time index tracked by xo_ld/ho_ld, then advances them one step.
#define PREF(p)                                                               \
    {                                                                         \
        _Pragma("unroll") for (int r_ = 0; r_ < 4; r_++) {                    \
            GLOAD(p.xr[r_], xo_ld[r_], xp, "0");                              \
            GLOAD(p.xz[r_], xo_ld[r_], xp, "256");                            \
            GLOAD(p.xn[r_], xo_ld[r_], xp, "512");                            \
            GLOAD(p.rv[r_], ho_ld[r_], hb, "0");                              \
        }                                                                     \
        _Pragma("unroll") for (int r_ = 0; r_ < 4; r_++) {                    \
            xo_ld[r_] += XS;                                                  \
            ho_ld[r_] += HS;                                                  \
        }                                                                     \
    }

#define GSTEP(PAR, p, WN, DP)                                                 \
    {                                                                         \
        asm volatile("s_waitcnt vmcnt(" #WN ")");                             \
        __builtin_amdgcn_sched_barrier(0);                                    \
        float xrf[4], xzf[4], xnf[4], rvf[4];                                 \
        _Pragma("unroll") for (int r_ = 0; r_ < 4; r_++) {                    \
            xrf[r_] = __uint_as_float(p.xr[r_] << 16);                        \
            xzf[r_] = __uint_as_float(p.xz[r_] << 16);                        \
            xnf[r_] = __uint_as_float(p.xn[r_] << 16);                        \
            rvf[r_] = __uint_as_float(p.rv[r_] << 16);                        \
        }                                                                     \
        if (DP) {                                                             \
            PREF(p)                                                           \
        }                                                                     \
        const ushort* hrd = lds + (PAR)*2176 + ln * 136 + kq * 8;             \
        sh8 a0 = *(const sh8*)(hrd);                                          \
        sh8 a1 = *(const sh8*)(hrd + 32);                                     \
        sh8 a2 = *(const sh8*)(hrd + 64);                                     \
        sh8 a3 = *(const sh8*)(hrd + 96);                                     \
        f32x4 accr = (f32x4){0.f, 0.f, 0.f, 0.f};                             \
        f32x4 accz = accr, accn = accr;                                       \
        accr = __builtin_amdgcn_mfma_f32_16x16x32_bf16(a0, bfrag[0][0], accr, 0, 0, 0); \
        accz = __builtin_amdgcn_mfma_f32_16x16x32_bf16(a0, bfrag[1][0], accz, 0, 0, 0); \
        accn = __builtin_amdgcn_mfma_f32_16x16x32_bf16(a0, bfrag[2][0], accn, 0, 0, 0); \
        accr = __builtin_amdgcn_mfma_f32_16x16x32_bf16(a1, bfrag[0][1], accr, 0, 0, 0); \
        accz = __builtin_amdgcn_mfma_f32_16x16x32_bf16(a1, bfrag[1][1], accz, 0, 0, 0); \
        accn = __builtin_amdgcn_mfma_f32_16x16x32_bf16(a1, bfrag[2][1], accn, 0, 0, 0); \
        accr = __builtin_amdgcn_mfma_f32_16x16x32_bf16(a2, bfrag[0][2], accr, 0, 0, 0); \
        accz = __builtin_amdgcn_mfma_f32_16x16x32_bf16(a2, bfrag[1][2], accz, 0, 0, 0); \
        accn = __builtin_amdgcn_mfma_f32_16x16x32_bf16(a2, bfrag[2][2], accn, 0, 0, 0); \
        accr = __builtin_amdgcn_mfma_f32_16x16x32_bf16(a3, bfrag[0][3], accr, 0, 0, 0); \
        accz = __builtin_amdgcn_mfma_f32_16x16x32_bf16(a3, bfrag[1][3], accz, 0, 0, 0); \
        accn = __builtin_amdgcn_mfma_f32_16x16x32_bf16(a3, bfrag[2][3], accn, 0, 0, 0); \
        float hv[4], sv[4];                                                   \
        _Pragma("unroll") for (int r_ = 0; r_ < 4; r_++) {                    \
            float rg = sigmf(xrf[r_] + accr[r_] + bh_r);                      \
            float zg = sigmf(xzf[r_] + accz[r_] + bh_z);                      \
            float ng = tanhf2(fmaf(rg, accn[r_] + bh_n, xnf[r_]));            \
            float h = fmaf(zg, hstate[r_] - ng, ng);                          \
            hstate[r_] = h;                                                   \
            hv[r_] = h;                                                       \
            sv[r_] = h + rvf[r_];                                             \
        }                                                                     \
        uint u01 = cvt_pk_bf16(hv[0], hv[1]);                                 \
        uint u23 = cvt_pk_bf16(hv[2], hv[3]);                                 \
        ushort* hw = lds + (1 - (PAR)) * 2176 + (kq * 4) * 136 + jcol;        \
        hw[0] = (ushort)u01;                                                  \
        hw[136] = (ushort)(u01 >> 16);                                        \
        hw[272] = (ushort)u23;                                                \
        hw[408] = (ushort)(u23 >> 16);                                        \
        uint s01 = cvt_pk_bf16(sv[0], sv[1]);                                 \
        uint s23 = cvt_pk_bf16(sv[2], sv[3]);                                 \
        uint s01h = s01 >> 16, s23h = s23 >> 16;                              \
        GSTORE(ho_st[0], s01, hb);                                            \
        GSTORE(ho_st[1], s01h, hb);                                           \
        GSTORE(ho_st[2], s23, hb);                                            \
        GSTORE(ho_st[3], s23h, hb);                                           \
        _Pragma("unroll") for (int r_ = 0; r_ < 4; r_++) ho_st[r_] += HS;     \
        asm volatile("s_waitcnt lgkmcnt(0)");                                 \
        __builtin_amdgcn_sched_barrier(0);                                    \
        __builtin_amdgcn_s_barrier();                                         \
        __builtin_amdgcn_sched_barrier(0);                                    \
    }

template <int DS>  // +1 forward, -1 backward
__device__ __forceinline__ void gru_impl(const ushort* __restrict__ xp,
                                         const float* __restrict__ Whh_l,
                                         const float* __restrict__ bhh_l,
                                         ushort* __restrict__ hb,
                                         int dir, int b_base, int t,
                                         ushort* lds) {
    constexpr int XS = DS * 1536;  // xp row stride per time step, bytes
    constexpr int HS = DS * 512;   // hb row stride per time step, bytes
    const int w = t >> 6, l = t & 63;
    const int ln = l & 15, kq = l >> 4;
    const int jcol = (w << 4) + ln;

    const float* Wd = Whh_l + (size_t)dir * 384 * 128;
    const float* bhh_d = bhh_l + dir * 384;

    // Whh B-fragments, bf16, resident in VGPRs (prologue; converted
    // immediately so compiler waits resolve before the main loop).
    sh8 bfrag[3][4];
#pragma unroll
    for (int g = 0; g < 3; g++)
#pragma unroll
        for (int kt = 0; kt < 4; kt++) {
            const float4* wp =
                (const float4*)(Wd + (size_t)(g * 128 + jcol) * 128 + kt * 32 + kq * 8);
            float4 w0 = wp[0], w1 = wp[1];
            uint4 pv;
            pv.x = pack2(w0.x, w0.y);
            pv.y = pack2(w0.z, w0.w);
            pv.z = pack2(w1.x, w1.y);
            pv.w = pack2(w1.z, w1.w);
            bfrag[g][kt] = *(sh8*)&pv;
        }

    const float bh_r = bhh_d[jcol];
    const float bh_z = bhh_d[128 + jcol];
    const float bh_n = bhh_d[256 + jcol];
    // Force bias loads (and their waits) to resolve in the prologue so the
    // compiler emits no vmem waits inside the main loop.
    asm volatile("" ::"v"(bh_r), "v"(bh_z), "v"(bh_n));

    // Running byte voffsets. *_ld tracks the NEXT load target time; *_st
    // tracks the current store (= compute) time.
    const int t0 = (DS > 0) ? 0 : 511;
    int xo_ld[4], ho_ld[4], ho_st[4];
#pragma unroll
    for (int r = 0; r < 4; r++) {
        int row = (b_base + kq * 4 + r) * 512 + t0;
        xo_ld[r] = row * 1536 + (dir * 384 + jcol) * 2;
        ho_ld[r] = row * 512 + (dir * 128 + jcol) * 2;
        ho_st[r] = ho_ld[r];
    }

    float hstate[4] = {0.f, 0.f, 0.f, 0.f};

    // h0 = 0 in buffer 0
    for (int i = t; i < 16 * 136; i += 512) lds[i] = 0;
    __syncthreads();  // full drain once; vmcnt==0 after this point

    PF pA, pB;
    PREF(pA)  // time t0      (16 loads)
    PREF(pB)  // time t0+1    (16 loads)

    // Peeled first pair: exact counts (pA: 16 outstanding after = pB's
    // loads; pB: 20 = step0's 16 loads + 4 stores).
    GSTEP(0, pA, 16, 1)  // s = 0
    GSTEP(1, pB, 20, 1)  // s = 1
    for (int s = 2; s < 510; s += 2) {
        GSTEP(0, pA, 24, 1)
        GSTEP(1, pB, 24, 1)
    }
    // Tail: no prefetch (times 512/513 OOB). Step 510 still has the full
    // 24 younger ops; step 511 has only 8 (4+4 stores, no 510 loads).
    GSTEP(0, pA, 24, 0)  // s = 510
    GSTEP(1, pB, 8, 0)   // s = 511
}

__global__ __launch_bounds__(512, 1) void k_gru(const ushort* __restrict__ xp,
                                                const float* __restrict__ Whh_l,
                                                const float* __restrict__ bhh_l,
                                                ushort* __restrict__ hb) {
    __shared__ __align__(16) ushort lds[2 * 16 * 136];
    const int dir = blockIdx.x & 1;
    const int b_base = (blockIdx.x >> 1) << 4;
    if (dir == 0)
        gru_impl<1>(xp, Whh_l, bhh_l, hb, dir, b_base, threadIdx.x, lds);
    else
        gru_impl<-1>(xp, Whh_l, bhh_l, hb, dir, b_base, threadIdx.x, lds);
}

// ---------------------------------------------------------------------------
// Host launcher. fp32 inputs AND fp32 output; bf16 internally for MFMA.
// Scratch confined to 64 MiB:
//   [0, 48M)  xp (bf16 32768x768) — also hosts embA, then g (16 MiB each)
//   [48,64M)  hb (bf16 32768x256) — W1 out, GRU layers update in place
// ---------------------------------------------------------------------------
extern "C" void kernel_launch(void* const* d_in, const int* in_sizes, int n_in,
                              void* d_out, int out_size, void* d_ws, size_t ws_size,
                              hipStream_t stream) {
    const void* x = d_in[0];
    const float* embed = (const float*)d_in[1];
    const float* W1 = (const float*)d_in[2];
    const float* b1 = (const float*)d_in[3];
    const float* Wih = (const float*)d_in[4];  // [2][2][384][256]
    const float* Whh = (const float*)d_in[5];  // [2][2][384][128]
    const float* bih = (const float*)d_in[6];  // [2][2][384]
    const float* bhh = (const float*)d_in[7];  // [2][2][384]
    const float* W2 = (const float*)d_in[8];
    const float* b2 = (const float*)d_in[9];
    const float* W3 = (const float*)d_in[10];
    const float* b3 = (const float*)d_in[11];

    char* ws = (char*)d_ws;
    ushort* xp = (ushort*)ws;                         // [0, 48M)
    ushort* hb = (ushort*)(ws + 32768ull * 768 * 2);  // [48M, 64M)
    ushort* embA = xp;  // 16 MiB slot, dead after W1 GEMM
    ushort* g = xp;     // reused after last GRU
    int* xflag = (int*)hb;  // transient; dead after k_gather

    // detect x index width, then gather + W1: hb = bf16(embA @ W1^T + b1)
    k_detx<<<1, 256, 0, stream>>>((const uint*)x, xflag);
    k_gather<<<4096, 256, 0, stream>>>(x, embed, xflag, embA);
    k_gemm_bt<<<dim3(256, 2), 256, 0, stream>>>(embA, W1, b1, hb, (float*)0,
                                                32768, 256, 256, 0);

    // layer 0: xp = hb @ Wih[0]^T + bih[0]; GRU updates hb in place
    k_gemm_bt<<<dim3(256, 6), 256, 0, stream>>>(hb, Wih, bih, xp, (float*)0,
                                                32768, 768, 256, 0);
    k_gru<<<8, 512, 0, stream>>>(xp, Whh, bhh, hb);

    // layer 1
    k_gemm_bt<<<dim3(256, 6), 256, 0, stream>>>(hb, Wih + 196608, bih + 768,
                                                xp, (float*)0, 32768, 768, 256, 0);
    k_gru<<<8, 512, 0, stream>>>(xp, Whh + 98304, bhh + 768, hb);

    // head: g = bf16(GELU(hb @ W2^T + b2)); d_out = fp32(g @ W3^T + b3)
    k_gemm_bt<<<dim3(256, 2), 256, 0, stream>>>(hb, W2, b2, g, (float*)0,
                                                32768, 256, 256, 1);
    k_gemm_bt<<<dim3(256, 1), 256, 0, stream>>>(g, W3, b3, (ushort*)0,
                                                (float*)d_out, 32768, 50, 256, 0);
}

// Round 6
// 887.618 us; speedup vs baseline: 1.4503x; 1.2278x over previous
//
#include <hip/hip_runtime.h>

typedef unsigned int uint;
typedef unsigned short ushort;

typedef __attribute__((ext_vector_type(8))) short sh8;
typedef __attribute__((ext_vector_type(4))) float f32x4;

__device__ __forceinline__ ushort f2b(float f) {
    uint x = __float_as_uint(f);
    x += 0x7fffu + ((x >> 16) & 1u);
    return (ushort)(x >> 16);
}
__device__ __forceinline__ float b2f(ushort u) {
    return __uint_as_float(((uint)u) << 16);
}
__device__ __forceinline__ uint pack2(float a, float b) {
    return (uint)f2b(a) | ((uint)f2b(b) << 16);
}
// RTNE pack of two f32 -> two bf16 in one instruction.
__device__ __forceinline__ uint cvt_pk_bf16(float lo, float hi) {
    uint r;
    asm("v_cvt_pk_bf16_f32 %0, %1, %2" : "=v"(r) : "v"(lo), "v"(hi));
    return r;
}
__device__ __forceinline__ float frcp(float x) { return __builtin_amdgcn_rcpf(x); }
__device__ __forceinline__ float sigmf(float x) { return frcp(1.0f + __expf(-x)); }
__device__ __forceinline__ float tanhf2(float y) {
    return fmaf(2.0f, frcp(1.0f + __expf(-2.0f * y)), -1.0f);
}

// ---------------------------------------------------------------------------
// Index-width detector for x (robustness; x believed int32).
// ---------------------------------------------------------------------------
__global__ __launch_bounds__(256) void k_detx(const uint* __restrict__ xw,
                                              int* __restrict__ flag) {
    __shared__ int sh[256];
    int t = threadIdx.x;
    int c = 0;
    for (int i = t; i < 2048; i += 256) c += (xw[2 * i + 1] == 0u) ? 1 : 0;
    sh[t] = c;
    __syncthreads();
    if (t == 0) {
        int s = 0;
        for (int i = 0; i < 256; i++) s += sh[i];
        flag[0] = (s >= 1843) ? 1 : 0;  // >=90% zeros -> int64
    }
}

// ---------------------------------------------------------------------------
// Embedding gather, fp32 -> bf16, index-width aware.
// ---------------------------------------------------------------------------
__global__ __launch_bounds__(256) void k_gather(const void* __restrict__ x,
                                                const float* __restrict__ embed,
                                                const int* __restrict__ flag,
                                                ushort* __restrict__ out) {
    int chunk = blockIdx.x * 256 + threadIdx.x;
    int row = chunk >> 5;
    int c = chunk & 31;
    int v;
    if (flag[0]) {
        v = (int)((const uint*)x)[2 * row];
    } else {
        v = ((const int*)x)[row];
    }
    v = min(max(v, 0), 49999);
    const float4* e = (const float4*)&embed[(size_t)v * 256 + (size_t)c * 8];
    float4 a = e[0], b = e[1];
    uint4 pv;
    pv.x = pack2(a.x, a.y);
    pv.y = pack2(a.z, a.w);
    pv.z = pack2(b.x, b.y);
    pv.w = pack2(b.z, b.w);
    *(uint4*)&out[(size_t)row * 256 + (size_t)c * 8] = pv;
}

// ---------------------------------------------------------------------------
// GEMM (verified at baseline): C = A(bf16) * W^T(fp32 inline->bf16) + bias,
// optional GELU; bf16 Cb and/or fp32 Cf outputs. Plain __syncthreads.
// ---------------------------------------------------------------------------
__global__ __launch_bounds__(256) void k_gemm_bt(const ushort* __restrict__ A,
                                                 const float* __restrict__ Wf,
                                                 const float* __restrict__ bias,
                                                 ushort* __restrict__ Cb,
                                                 float* __restrict__ Cf,
                                                 int M, int N, int K, int gelu) {
    __shared__ __align__(16) ushort Al[128 * 32];
    __shared__ __align__(16) ushort Bl[128 * 32];
    int tid = threadIdx.x;
    int bm = blockIdx.x, bn = blockIdx.y;
    int wid = tid >> 6, lane = tid & 63;
    int ln = lane & 15, kq = lane >> 4;
    int wm = (wid & 1) * 64, wn = (wid >> 1) * 64;
    int rowA0 = bm * 128, rowB0 = bn * 128;

    f32x4 acc[4][4];
#pragma unroll
    for (int i = 0; i < 4; i++)
#pragma unroll
        for (int j = 0; j < 4; j++) acc[i][j] = (f32x4){0.f, 0.f, 0.f, 0.f};

    for (int kt = 0; kt < K; kt += 32) {
#pragma unroll
        for (int c = tid; c < 512; c += 256) {
            int r = c >> 2, c8 = (c & 3) * 8;
            *(uint4*)&Al[r * 32 + c8] =
                *(const uint4*)&A[(size_t)(rowA0 + r) * K + kt + c8];
            int nb = rowB0 + r;
            uint4 bv = {0u, 0u, 0u, 0u};
            if (nb < N) {
                const float4* wp = (const float4*)&Wf[(size_t)nb * K + kt + c8];
                float4 w0 = wp[0], w1 = wp[1];
                bv.x = pack2(w0.x, w0.y);
                bv.y = pack2(w0.z, w0.w);
                bv.z = pack2(w1.x, w1.y);
                bv.w = pack2(w1.z, w1.w);
            }
            *(uint4*)&Bl[r * 32 + c8] = bv;
        }
        __syncthreads();
        sh8 af[4], bfr[4];
#pragma unroll
        for (int i = 0; i < 4; i++)
            af[i] = *(const sh8*)&Al[(wm + i * 16 + ln) * 32 + kq * 8];
#pragma unroll
        for (int j = 0; j < 4; j++)
            bfr[j] = *(const sh8*)&Bl[(wn + j * 16 + ln) * 32 + kq * 8];
#pragma unroll
        for (int i = 0; i < 4; i++)
#pragma unroll
            for (int j = 0; j < 4; j++)
                acc[i][j] = __builtin_amdgcn_mfma_f32_16x16x32_bf16(
                    af[i], bfr[j], acc[i][j], 0, 0, 0);
        __syncthreads();
    }

#pragma unroll
    for (int i = 0; i < 4; i++)
#pragma unroll
        for (int j = 0; j < 4; j++) {
            int col = rowB0 + wn + j * 16 + ln;
            if (col >= N) continue;
            float bv = bias[col];
#pragma unroll
            for (int reg = 0; reg < 4; reg++) {
                int row = rowA0 + wm + i * 16 + kq * 4 + reg;
                float v = acc[i][j][reg] + bv;
                if (gelu) v = 0.5f * v * (1.0f + erff(v * 0.70710678118f));
                if (Cb) Cb[(size_t)row * N + col] = f2b(v);
                if (Cf) Cf[(size_t)row * N + col] = v;
            }
        }
}

// ---------------------------------------------------------------------------
// GRU recurrence v7 — 32 blocks (4 batches x 1 dir each), all-lane gates.
// Theory (r5 counters): per-CU VALU issue (~1245 cy/SIMD/step) dominated the
// step; per-CU work is invariant to wave redistribution, so spread sequences
// over 4x more CUs AND make every lane do exactly ONE h-output's gate math.
// MFMA structure unchanged (12 x 16x16x32 per wave; A rows 4..15 are zeros
// from init, their C rows discarded). After MFMA, only kq=0 lanes hold valid
// C rows 0..3; redistribute via 12 ds_bpermute (DS pipe) + 9 cndmask so lane
// l owns output (b = l>>4, col = w*16 + (l&15)). Per thread per step: 4
// global loads (asm, counted vmcnt), 1 store, 1 ds_write_b16, gates depth 1.
// vmcnt stream (4 loads + 1 store per step, distance-2 prefetch, FIFO
// retirement): W0=4, W1=5, steady/W510=6, W511=2.
// ---------------------------------------------------------------------------
struct PF {
    uint xr, xz, xn, rv;
};

#define GLOAD(dst, off, base, IMM)                                            \
    asm volatile("global_load_ushort %0, %1, %2 offset:" IMM                  \
                 : "=v"(dst)                                                  \
                 : "v"(off), "s"(base))

#define GSTORE(off, data, base)                                               \
    asm volatile("global_store_short %0, %1, %2" ::"v"(off), "v"(data),       \
                 "s"(base))

__device__ __forceinline__ float sel4(f32x4 a, int bpa, bool b1, bool b2) {
    int p0 = __builtin_amdgcn_ds_bpermute(bpa, __float_as_int(a[0]));
    int p1 = __builtin_amdgcn_ds_bpermute(bpa, __float_as_int(a[1]));
    int p2 = __builtin_amdgcn_ds_bpermute(bpa, __float_as_int(a[2]));
    int p3 = __builtin_amdgcn_ds_bpermute(bpa, __float_as_int(a[3]));
    int lo = b1 ? p1 : p0;
    int hi = b1 ? p3 : p2;
    return __int_as_float(b2 ? hi : lo);
}

#define PREF(p)                                                               \
    {                                                                         \
        GLOAD(p.xr, xo_ld, xp, "0");                                          \
        GLOAD(p.xz, xo_ld, xp, "256");                                        \
        GLOAD(p.xn, xo_ld, xp, "512");                                        \
        GLOAD(p.rv, ho_ld, hb, "0");                                          \
        xo_ld += XS;                                                          \
        ho_ld += HS;                                                          \
    }

#define GSTEP(PAR, p, WN, DP)                                                 \
    {                                                                         \
        asm volatile("s_waitcnt vmcnt(" #WN ")");                             \
        __builtin_amdgcn_sched_barrier(0);                                    \
        float xr = __uint_as_float(p.xr << 16);                               \
        float xz = __uint_as_float(p.xz << 16);                               \
        float xn = __uint_as_float(p.xn << 16);                               \
        float rv = __uint_as_float(p.rv << 16);                               \
        if (DP) {                                                             \
            PREF(p)                                                           \
        }                                                                     \
        const ushort* hrd = lds + (PAR)*2176 + ln * 136 + kq * 8;             \
        sh8 a0 = *(const sh8*)(hrd);                                          \
        sh8 a1 = *(const sh8*)(hrd + 32);                                     \
        sh8 a2 = *(const sh8*)(hrd + 64);                                     \
        sh8 a3 = *(const sh8*)(hrd + 96);                                     \
        f32x4 accr = (f32x4){0.f, 0.f, 0.f, 0.f};                             \
        f32x4 accz = accr, accn = accr;                                       \
        accr = __builtin_amdgcn_mfma_f32_16x16x32_bf16(a0, bfrag[0][0], accr, 0, 0, 0); \
        accz = __builtin_amdgcn_mfma_f32_16x16x32_bf16(a0, bfrag[1][0], accz, 0, 0, 0); \
        accn = __builtin_amdgcn_mfma_f32_16x16x32_bf16(a0, bfrag[2][0], accn, 0, 0, 0); \
        accr = __builtin_amdgcn_mfma_f32_16x16x32_bf16(a1, bfrag[0][1], accr, 0, 0, 0); \
        accz = __builtin_amdgcn_mfma_f32_16x16x32_bf16(a1, bfrag[1][1], accz, 0, 0, 0); \
        accn = __builtin_amdgcn_mfma_f32_16x16x32_bf16(a1, bfrag[2][1], accn, 0, 0, 0); \
        accr = __builtin_amdgcn_mfma_f32_16x16x32_bf16(a2, bfrag[0][2], accr, 0, 0, 0); \
        accz = __builtin_amdgcn_mfma_f32_16x16x32_bf16(a2, bfrag[1][2], accz, 0, 0, 0); \
        accn = __builtin_amdgcn_mfma_f32_16x16x32_bf16(a2, bfrag[2][2], accn, 0, 0, 0); \
        accr = __builtin_amdgcn_mfma_f32_16x16x32_bf16(a3, bfrag[0][3], accr, 0, 0, 0); \
        accz = __builtin_amdgcn_mfma_f32_16x16x32_bf16(a3, bfrag[1][3], accz, 0, 0, 0); \
        accn = __builtin_amdgcn_mfma_f32_16x16x32_bf16(a3, bfrag[2][3], accn, 0, 0, 0); \
        float ar = sel4(accr, bpa, b1, b2);                                   \
        float az = sel4(accz, bpa, b1, b2);                                   \
        float an = sel4(accn, bpa, b1, b2);                                   \
        float rg = sigmf(xr + ar + bh_r);                                     \
        float zg = sigmf(xz + az + bh_z);                                     \
        float ng = tanhf2(fmaf(rg, an + bh_n, xn));                           \
        float h = fmaf(zg, hstate - ng, ng);                                  \
        hstate = h;                                                           \
        float sv = h + rv;                                                    \
        uint pk = cvt_pk_bf16(h, sv);                                         \
        lds[(1 - (PAR)) * 2176 + ob * 136 + jcol] = (ushort)pk;               \
        uint svb = pk >> 16;                                                  \
        GSTORE(ho_st, svb, hb);                                               \
        ho_st += HS;                                                          \
        asm volatile("s_waitcnt lgkmcnt(0)");                                 \
        __builtin_amdgcn_sched_barrier(0);                                    \
        __builtin_amdgcn_s_barrier();                                         \
        __builtin_amdgcn_sched_barrier(0);                                    \
    }

template <int DS>  // +1 forward, -1 backward
__device__ __forceinline__ void gru_impl(const ushort* __restrict__ xp,
                                         const float* __restrict__ Whh_l,
                                         const float* __restrict__ bhh_l,
                                         ushort* __restrict__ hb,
                                         int dir, int b_base, int t,
                                         ushort* lds) {
    constexpr int XS = DS * 1536;  // xp row stride per time step, bytes
    constexpr int HS = DS * 512;   // hb row stride per time step, bytes
    const int w = t >> 6, l = t & 63;
    const int ln = l & 15, kq = l >> 4;
    const int jcol = (w << 4) + ln;  // output col (and B-frag row)
    const int ob = kq;               // output batch index 0..3
    const int bpa = ln * 4;          // bpermute src: lane ln holds C rows
    const bool b1 = (ob & 1) != 0, b2 = (ob & 2) != 0;

    const float* Wd = Whh_l + (size_t)dir * 384 * 128;
    const float* bhh_d = bhh_l + dir * 384;

    // Whh B-fragments, bf16, resident in VGPRs.
    sh8 bfrag[3][4];
#pragma unroll
    for (int g = 0; g < 3; g++)
#pragma unroll
        for (int kt = 0; kt < 4; kt++) {
            const float4* wp =
                (const float4*)(Wd + (size_t)(g * 128 + jcol) * 128 + kt * 32 + kq * 8);
            float4 w0 = wp[0], w1 = wp[1];
            uint4 pv;
            pv.x = pack2(w0.x, w0.y);
            pv.y = pack2(w0.z, w0.w);
            pv.z = pack2(w1.x, w1.y);
            pv.w = pack2(w1.z, w1.w);
            bfrag[g][kt] = *(sh8*)&pv;
        }

    const float bh_r = bhh_d[jcol];
    const float bh_z = bhh_d[128 + jcol];
    const float bh_n = bhh_d[256 + jcol];
    asm volatile("" ::"v"(bh_r), "v"(bh_z), "v"(bh_n));

    // Running byte voffsets for THIS lane's single output (b_base+ob, jcol).
    const int t0 = (DS > 0) ? 0 : 511;
    int row0 = (b_base + ob) * 512 + t0;
    int xo_ld = row0 * 1536 + (dir * 384 + jcol) * 2;
    int ho_ld = row0 * 512 + (dir * 128 + jcol) * 2;
    int ho_st = ho_ld;

    float hstate = 0.f;

    // zero ALL of both h buffers once: rows 4..15 stay zero forever (their
    // MFMA C rows are discarded; zeros keep them NaN-free).
    for (int i = t; i < 2 * 16 * 136; i += 512) lds[i] = 0;
    __syncthreads();  // full drain; vmcnt==0 from here

    PF pA, pB;
    PREF(pA)  // t0   (4 loads)
    PREF(pB)  // t0+1 (4 loads)

    GSTEP(0, pA, 4, 1)  // s = 0
    GSTEP(1, pB, 5, 1)  // s = 1
    for (int s = 2; s < 510; s += 2) {
        GSTEP(0, pA, 6, 1)
        GSTEP(1, pB, 6, 1)
    }
    GSTEP(0, pA, 6, 0)  // s = 510 (no prefetch)
    GSTEP(1, pB, 2, 0)  // s = 511
}

__global__ __launch_bounds__(512, 1) void k_gru(const ushort* __restrict__ xp,
                                                const float* __restrict__ Whh_l,
                                                const float* __restrict__ bhh_l,
                                                ushort* __restrict__ hb) {
    __shared__ __align__(16) ushort lds[2 * 16 * 136];
    const int dir = blockIdx.x & 1;
    const int b_base = (blockIdx.x >> 1) << 2;  // 4 batches per block
    if (dir == 0)
        gru_impl<1>(xp, Whh_l, bhh_l, hb, dir, b_base, threadIdx.x, lds);
    else
        gru_impl<-1>(xp, Whh_l, bhh_l, hb, dir, b_base, threadIdx.x, lds);
}

// ---------------------------------------------------------------------------
// Host launcher. fp32 inputs AND fp32 output; bf16 internally for MFMA.
// Scratch confined to 64 MiB:
//   [0, 48M)  xp (bf16 32768x768) — also hosts embA, then g (16 MiB each)
//   [48,64M)  hb (bf16 32768x256) — W1 out, GRU layers update in place
// ---------------------------------------------------------------------------
extern "C" void kernel_launch(void* const* d_in, const int* in_sizes, int n_in,
                              void* d_out, int out_size, void* d_ws, size_t ws_size,
                              hipStream_t stream) {
    const void* x = d_in[0];
    const float* embed = (const float*)d_in[1];
    const float* W1 = (const float*)d_in[2];
    const float* b1 = (const float*)d_in[3];
    const float* Wih = (const float*)d_in[4];  // [2][2][384][256]
    const float* Whh = (const float*)d_in[5];  // [2][2][384][128]
    const float* bih = (const float*)d_in[6];  // [2][2][384]
    const float* bhh = (const float*)d_in[7];  // [2][2][384]
    const float* W2 = (const float*)d_in[8];
    const float* b2 = (const float*)d_in[9];
    const float* W3 = (const float*)d_in[10];
    const float* b3 = (const float*)d_in[11];

    char* ws = (char*)d_ws;
    ushort* xp = (ushort*)ws;                         // [0, 48M)
    ushort* hb = (ushort*)(ws + 32768ull * 768 * 2);  // [48M, 64M)
    ushort* embA = xp;  // 16 MiB slot, dead after W1 GEMM
    ushort* g = xp;     // reused after last GRU
    int* xflag = (int*)hb;  // transient; dead after k_gather

    // detect x index width, then gather + W1: hb = bf16(embA @ W1^T + b1)
    k_detx<<<1, 256, 0, stream>>>((const uint*)x, xflag);
    k_gather<<<4096, 256, 0, stream>>>(x, embed, xflag, embA);
    k_gemm_bt<<<dim3(256, 2), 256, 0, stream>>>(embA, W1, b1, hb, (float*)0,
                                                32768, 256, 256, 0);

    // layer 0: xp = hb @ Wih[0]^T + bih[0]; GRU updates hb in place
    k_gemm_bt<<<dim3(256, 6), 256, 0, stream>>>(hb, Wih, bih, xp, (float*)0,
                                                32768, 768, 256, 0);
    k_gru<<<32, 512, 0, stream>>>(xp, Whh, bhh, hb);

    // layer 1
    k_gemm_bt<<<dim3(256, 6), 256, 0, stream>>>(hb, Wih + 196608, bih + 768,
                                                xp, (float*)0, 32768, 768, 256, 0);
    k_gru<<<32, 512, 0, stream>>>(xp, Whh + 98304, bhh + 768, hb);

    // head: g = bf16(GELU(hb @ W2^T + b2)); d_out = fp32(g @ W3^T + b3)
    k_gemm_bt<<<dim3(256, 2), 256, 0, stream>>>(hb, W2, b2, g, (float*)0,
                                                32768, 256, 256, 1);
    k_gemm_bt<<<dim3(256, 1), 256, 0, stream>>>(g, W3, b3, (ushort*)0,
                                                (float*)d_out, 32768, 50, 256, 0);
}

// Round 7
// 674.049 us; speedup vs baseline: 1.9098x; 1.3168x over previous
//
#include <hip/hip_runtime.h>

typedef unsigned int uint;
typedef unsigned short ushort;

typedef __attribute__((ext_vector_type(8))) short sh8;
typedef __attribute__((ext_vector_type(4))) float f32x4;

__device__ __forceinline__ ushort f2b(float f) {
    uint x = __float_as_uint(f);
    x += 0x7fffu + ((x >> 16) & 1u);
    return (ushort)(x >> 16);
}
__device__ __forceinline__ float b2f(ushort u) {
    return __uint_as_float(((uint)u) << 16);
}
__device__ __forceinline__ uint pack2(float a, float b) {
    return (uint)f2b(a) | ((uint)f2b(b) << 16);
}
// RTNE pack of two f32 -> two bf16 in one instruction.
__device__ __forceinline__ uint cvt_pk_bf16(float lo, float hi) {
    uint r;
    asm("v_cvt_pk_bf16_f32 %0, %1, %2" : "=v"(r) : "v"(lo), "v"(hi));
    return r;
}
__device__ __forceinline__ float frcp(float x) { return __builtin_amdgcn_rcpf(x); }
__device__ __forceinline__ float sigmf(float x) { return frcp(1.0f + __expf(-x)); }
__device__ __forceinline__ float tanhf2(float y) {
    return fmaf(2.0f, frcp(1.0f + __expf(-2.0f * y)), -1.0f);
}

// ---------------------------------------------------------------------------
// Index-width detector for x (robustness; x believed int32).
// ---------------------------------------------------------------------------
__global__ __launch_bounds__(256) void k_detx(const uint* __restrict__ xw,
                                              int* __restrict__ flag) {
    __shared__ int sh[256];
    int t = threadIdx.x;
    int c = 0;
    for (int i = t; i < 2048; i += 256) c += (xw[2 * i + 1] == 0u) ? 1 : 0;
    sh[t] = c;
    __syncthreads();
    if (t == 0) {
        int s = 0;
        for (int i = 0; i < 256; i++) s += sh[i];
        flag[0] = (s >= 1843) ? 1 : 0;  // >=90% zeros -> int64
    }
}

// ---------------------------------------------------------------------------
// Embedding gather, fp32 -> bf16, index-width aware.
// ---------------------------------------------------------------------------
__global__ __launch_bounds__(256) void k_gather(const void* __restrict__ x,
                                                const float* __restrict__ embed,
                                                const int* __restrict__ flag,
                                                ushort* __restrict__ out) {
    int chunk = blockIdx.x * 256 + threadIdx.x;
    int row = chunk >> 5;
    int c = chunk & 31;
    int v;
    if (flag[0]) {
        v = (int)((const uint*)x)[2 * row];
    } else {
        v = ((const int*)x)[row];
    }
    v = min(max(v, 0), 49999);
    const float4* e = (const float4*)&embed[(size_t)v * 256 + (size_t)c * 8];
    float4 a = e[0], b = e[1];
    uint4 pv;
    pv.x = pack2(a.x, a.y);
    pv.y = pack2(a.z, a.w);
    pv.z = pack2(b.x, b.y);
    pv.w = pack2(b.z, b.w);
    *(uint4*)&out[(size_t)row * 256 + (size_t)c * 8] = pv;
}

// ---------------------------------------------------------------------------
// GEMM (verified at baseline): C = A(bf16) * W^T(fp32 inline->bf16) + bias,
// optional GELU; bf16 Cb and/or fp32 Cf outputs. Plain __syncthreads.
// ---------------------------------------------------------------------------
__global__ __launch_bounds__(256) void k_gemm_bt(const ushort* __restrict__ A,
                                                 const float* __restrict__ Wf,
                                                 const float* __restrict__ bias,
                                                 ushort* __restrict__ Cb,
                                                 float* __restrict__ Cf,
                                                 int M, int N, int K, int gelu) {
    __shared__ __align__(16) ushort Al[128 * 32];
    __shared__ __align__(16) ushort Bl[128 * 32];
    int tid = threadIdx.x;
    int bm = blockIdx.x, bn = blockIdx.y;
    int wid = tid >> 6, lane = tid & 63;
    int ln = lane & 15, kq = lane >> 4;
    int wm = (wid & 1) * 64, wn = (wid >> 1) * 64;
    int rowA0 = bm * 128, rowB0 = bn * 128;

    f32x4 acc[4][4];
#pragma unroll
    for (int i = 0; i < 4; i++)
#pragma unroll
        for (int j = 0; j < 4; j++) acc[i][j] = (f32x4){0.f, 0.f, 0.f, 0.f};

    for (int kt = 0; kt < K; kt += 32) {
#pragma unroll
        for (int c = tid; c < 512; c += 256) {
            int r = c >> 2, c8 = (c & 3) * 8;
            *(uint4*)&Al[r * 32 + c8] =
                *(const uint4*)&A[(size_t)(rowA0 + r) * K + kt + c8];
            int nb = rowB0 + r;
            uint4 bv = {0u, 0u, 0u, 0u};
            if (nb < N) {
                const float4* wp = (const float4*)&Wf[(size_t)nb * K + kt + c8];
                float4 w0 = wp[0], w1 = wp[1];
                bv.x = pack2(w0.x, w0.y);
                bv.y = pack2(w0.z, w0.w);
                bv.z = pack2(w1.x, w1.y);
                bv.w = pack2(w1.z, w1.w);
            }
            *(uint4*)&Bl[r * 32 + c8] = bv;
        }
        __syncthreads();
        sh8 af[4], bfr[4];
#pragma unroll
        for (int i = 0; i < 4; i++)
            af[i] = *(const sh8*)&Al[(wm + i * 16 + ln) * 32 + kq * 8];
#pragma unroll
        for (int j = 0; j < 4; j++)
            bfr[j] = *(const sh8*)&Bl[(wn + j * 16 + ln) * 32 + kq * 8];
#pragma unroll
        for (int i = 0; i < 4; i++)
#pragma unroll
            for (int j = 0; j < 4; j++)
                acc[i][j] = __builtin_amdgcn_mfma_f32_16x16x32_bf16(
                    af[i], bfr[j], acc[i][j], 0, 0, 0);
        __syncthreads();
    }

#pragma unroll
    for (int i = 0; i < 4; i++)
#pragma unroll
        for (int j = 0; j < 4; j++) {
            int col = rowB0 + wn + j * 16 + ln;
            if (col >= N) continue;
            float bv = bias[col];
#pragma unroll
            for (int reg = 0; reg < 4; reg++) {
                int row = rowA0 + wm + i * 16 + kq * 4 + reg;
                float v = acc[i][j][reg] + bv;
                if (gelu) v = 0.5f * v * (1.0f + erff(v * 0.70710678118f));
                if (Cb) Cb[(size_t)row * N + col] = f2b(v);
                if (Cf) Cf[(size_t)row * N + col] = v;
            }
        }
}

// ---------------------------------------------------------------------------
// GRU recurrence v8 — replicated-A trick: zero DS redistribution.
// 32 blocks (4 batches x 1 dir), 512 threads, all-lane gates as v7.
// r6 counters: DS pipe serialized the step (12 ds_bpermute + 16-row A reads;
// 2.36M bank-conflict cycles). Fix: A-frag reads row (ln&3) so A rows 4..15
// are COPIES of rows 0..3 => C[4kq+r] = C_valid[r] => every lane's reg kq IS
// its output (batch kq): redistribution becomes 3 cndmask per gate, zero
// bpermutes. LDS h tile shrinks to [2][4][144] ushort (2.3KB): reads are
// 4-lane same-address broadcasts, 144-ushort stride = 72 dwords => rows 8
// banks apart (near conflict-free); write is 32 banks x 2-way (free).
// DS ops/wave/step: 17 -> 5. MFMA structure & counted-vmcnt stream (T3/T4)
// unchanged: 4 loads + 1 store per step, distance-2 prefetch, waits
// 4,5,6,...,6,2 — never 0.
// ---------------------------------------------------------------------------
struct PF {
    uint xr, xz, xn, rv;
};

#define GLOAD(dst, off, base, IMM)                                            \
    asm volatile("global_load_ushort %0, %1, %2 offset:" IMM                  \
                 : "=v"(dst)                                                  \
                 : "v"(off), "s"(base))

#define GSTORE(off, data, base)                                               \
    asm volatile("global_store_short %0, %1, %2" ::"v"(off), "v"(data),       \
                 "s"(base))

#define PREF(p)                                                               \
    {                                                                         \
        GLOAD(p.xr, xo_ld, xp, "0");                                          \
        GLOAD(p.xz, xo_ld, xp, "256");                                        \
        GLOAD(p.xn, xo_ld, xp, "512");                                        \
        GLOAD(p.rv, ho_ld, hb, "0");                                          \
        xo_ld += XS;                                                          \
        ho_ld += HS;                                                          \
    }

#define GSTEP(PAR, p, WN, DP)                                                 \
    {                                                                         \
        asm volatile("s_waitcnt vmcnt(" #WN ")");                             \
        __builtin_amdgcn_sched_barrier(0);                                    \
        float xr = __uint_as_float(p.xr << 16);                               \
        float xz = __uint_as_float(p.xz << 16);                               \
        float xn = __uint_as_float(p.xn << 16);                               \
        float rv = __uint_as_float(p.rv << 16);                               \
        if (DP) {                                                             \
            PREF(p)                                                           \
        }                                                                     \
        const ushort* hrd = lds + (PAR)*576 + (ln & 3) * 144 + kq * 8;        \
        sh8 a0 = *(const sh8*)(hrd);                                          \
        sh8 a1 = *(const sh8*)(hrd + 32);                                     \
        sh8 a2 = *(const sh8*)(hrd + 64);                                     \
        sh8 a3 = *(const sh8*)(hrd + 96);                                     \
        f32x4 accr = (f32x4){0.f, 0.f, 0.f, 0.f};                             \
        f32x4 accz = accr, accn = accr;                                       \
        accr = __builtin_amdgcn_mfma_f32_16x16x32_bf16(a0, bfrag[0][0], accr, 0, 0, 0); \
        accz = __builtin_amdgcn_mfma_f32_16x16x32_bf16(a0, bfrag[1][0], accz, 0, 0, 0); \
        accn = __builtin_amdgcn_mfma_f32_16x16x32_bf16(a0, bfrag[2][0], accn, 0, 0, 0); \
        accr = __builtin_amdgcn_mfma_f32_16x16x32_bf16(a1, bfrag[0][1], accr, 0, 0, 0); \
        accz = __builtin_amdgcn_mfma_f32_16x16x32_bf16(a1, bfrag[1][1], accz, 0, 0, 0); \
        accn = __builtin_amdgcn_mfma_f32_16x16x32_bf16(a1, bfrag[2][1], accn, 0, 0, 0); \
        accr = __builtin_amdgcn_mfma_f32_16x16x32_bf16(a2, bfrag[0][2], accr, 0, 0, 0); \
        accz = __builtin_amdgcn_mfma_f32_16x16x32_bf16(a2, bfrag[1][2], accz, 0, 0, 0); \
        accn = __builtin_amdgcn_mfma_f32_16x16x32_bf16(a2, bfrag[2][2], accn, 0, 0, 0); \
        accr = __builtin_amdgcn_mfma_f32_16x16x32_bf16(a3, bfrag[0][3], accr, 0, 0, 0); \
        accz = __builtin_amdgcn_mfma_f32_16x16x32_bf16(a3, bfrag[1][3], accz, 0, 0, 0); \
        accn = __builtin_amdgcn_mfma_f32_16x16x32_bf16(a3, bfrag[2][3], accn, 0, 0, 0); \
        float ar = b2 ? (b1 ? accr[3] : accr[2]) : (b1 ? accr[1] : accr[0]);  \
        float az = b2 ? (b1 ? accz[3] : accz[2]) : (b1 ? accz[1] : accz[0]);  \
        float an = b2 ? (b1 ? accn[3] : accn[2]) : (b1 ? accn[1] : accn[0]);  \
        float rg = sigmf(xr + ar + bh_r);                                     \
        float zg = sigmf(xz + az + bh_z);                                     \
        float ng = tanhf2(fmaf(rg, an + bh_n, xn));                           \
        float h = fmaf(zg, hstate - ng, ng);                                  \
        hstate = h;                                                           \
        float sv = h + rv;                                                    \
        uint pk = cvt_pk_bf16(h, sv);                                         \
        lds[(1 - (PAR)) * 576 + ob * 144 + jcol] = (ushort)pk;                \
        uint svb = pk >> 16;                                                  \
        GSTORE(ho_st, svb, hb);                                               \
        ho_st += HS;                                                          \
        asm volatile("s_waitcnt lgkmcnt(0)");                                 \
        __builtin_amdgcn_sched_barrier(0);                                    \
        __builtin_amdgcn_s_barrier();                                         \
        __builtin_amdgcn_sched_barrier(0);                                    \
    }

template <int DS>  // +1 forward, -1 backward
__device__ __forceinline__ void gru_impl(const ushort* __restrict__ xp,
                                         const float* __restrict__ Whh_l,
                                         const float* __restrict__ bhh_l,
                                         ushort* __restrict__ hb,
                                         int dir, int b_base, int t,
                                         ushort* lds) {
    constexpr int XS = DS * 1536;  // xp row stride per time step, bytes
    constexpr int HS = DS * 512;   // hb row stride per time step, bytes
    const int w = t >> 6, l = t & 63;
    const int ln = l & 15, kq = l >> 4;
    const int jcol = (w << 4) + ln;  // output col (and B-frag row)
    const int ob = kq;               // output batch index 0..3
    const bool b1 = (ob & 1) != 0, b2 = (ob & 2) != 0;

    const float* Wd = Whh_l + (size_t)dir * 384 * 128;
    const float* bhh_d = bhh_l + dir * 384;

    // Whh B-fragments, bf16, resident in VGPRs.
    sh8 bfrag[3][4];
#pragma unroll
    for (int g = 0; g < 3; g++)
#pragma unroll
        for (int kt = 0; kt < 4; kt++) {
            const float4* wp =
                (const float4*)(Wd + (size_t)(g * 128 + jcol) * 128 + kt * 32 + kq * 8);
            float4 w0 = wp[0], w1 = wp[1];
            uint4 pv;
            pv.x = pack2(w0.x, w0.y);
            pv.y = pack2(w0.z, w0.w);
            pv.z = pack2(w1.x, w1.y);
            pv.w = pack2(w1.z, w1.w);
            bfrag[g][kt] = *(sh8*)&pv;
        }

    const float bh_r = bhh_d[jcol];
    const float bh_z = bhh_d[128 + jcol];
    const float bh_n = bhh_d[256 + jcol];
    asm volatile("" ::"v"(bh_r), "v"(bh_z), "v"(bh_n));

    // Running byte voffsets for THIS lane's single output (b_base+ob, jcol).
    const int t0 = (DS > 0) ? 0 : 511;
    int row0 = (b_base + ob) * 512 + t0;
    int xo_ld = row0 * 1536 + (dir * 384 + jcol) * 2;
    int ho_ld = row0 * 512 + (dir * 128 + jcol) * 2;
    int ho_st = ho_ld;

    float hstate = 0.f;

    // zero both h buffers (4 rows x 144 each)
    for (int i = t; i < 2 * 576; i += 512) lds[i] = 0;
    __syncthreads();  // full drain; vmcnt==0 from here

    PF pA, pB;
    PREF(pA)  // t0   (4 loads)
    PREF(pB)  // t0+1 (4 loads)

    GSTEP(0, pA, 4, 1)  // s = 0
    GSTEP(1, pB, 5, 1)  // s = 1
    for (int s = 2; s < 510; s += 2) {
        GSTEP(0, pA, 6, 1)
        GSTEP(1, pB, 6, 1)
    }
    GSTEP(0, pA, 6, 0)  // s = 510 (no prefetch)
    GSTEP(1, pB, 2, 0)  // s = 511
}

__global__ __launch_bounds__(512, 1) void k_gru(const ushort* __restrict__ xp,
                                                const float* __restrict__ Whh_l,
                                                const float* __restrict__ bhh_l,
                                                ushort* __restrict__ hb) {
    __shared__ __align__(16) ushort lds[2 * 576];
    const int dir = blockIdx.x & 1;
    const int b_base = (blockIdx.x >> 1) << 2;  // 4 batches per block
    if (dir == 0)
        gru_impl<1>(xp, Whh_l, bhh_l, hb, dir, b_base, threadIdx.x, lds);
    else
        gru_impl<-1>(xp, Whh_l, bhh_l, hb, dir, b_base, threadIdx.x, lds);
}

// ---------------------------------------------------------------------------
// Host launcher. fp32 inputs AND fp32 output; bf16 internally for MFMA.
// Scratch confined to 64 MiB:
//   [0, 48M)  xp (bf16 32768x768) — also hosts embA, then g (16 MiB each)
//   [48,64M)  hb (bf16 32768x256) — W1 out, GRU layers update in place
// ---------------------------------------------------------------------------
extern "C" void kernel_launch(void* const* d_in, const int* in_sizes, int n_in,
                              void* d_out, int out_size, void* d_ws, size_t ws_size,
                              hipStream_t stream) {
    const void* x = d_in[0];
    const float* embed = (const float*)d_in[1];
    const float* W1 = (const float*)d_in[2];
    const float* b1 = (const float*)d_in[3];
    const float* Wih = (const float*)d_in[4];  // [2][2][384][256]
    const float* Whh = (const float*)d_in[5];  // [2][2][384][128]
    const float* bih = (const float*)d_in[6];  // [2][2][384]
    const float* bhh = (const float*)d_in[7];  // [2][2][384]
    const float* W2 = (const float*)d_in[8];
    const float* b2 = (const float*)d_in[9];
    const float* W3 = (const float*)d_in[10];
    const float* b3 = (const float*)d_in[11];

    char* ws = (char*)d_ws;
    ushort* xp = (ushort*)ws;                         // [0, 48M)
    ushort* hb = (ushort*)(ws + 32768ull * 768 * 2);  // [48M, 64M)
    ushort* embA = xp;  // 16 MiB slot, dead after W1 GEMM
    ushort* g = xp;     // reused after last GRU
    int* xflag = (int*)hb;  // transient; dead after k_gather

    // detect x index width, then gather + W1: hb = bf16(embA @ W1^T + b1)
    k_detx<<<1, 256, 0, stream>>>((const uint*)x, xflag);
    k_gather<<<4096, 256, 0, stream>>>(x, embed, xflag, embA);
    k_gemm_bt<<<dim3(256, 2), 256, 0, stream>>>(embA, W1, b1, hb, (float*)0,
                                                32768, 256, 256, 0);

    // layer 0: xp = hb @ Wih[0]^T + bih[0]; GRU updates hb in place
    k_gemm_bt<<<dim3(256, 6), 256, 0, stream>>>(hb, Wih, bih, xp, (float*)0,
                                                32768, 768, 256, 0);
    k_gru<<<32, 512, 0, stream>>>(xp, Whh, bhh, hb);

    // layer 1
    k_gemm_bt<<<dim3(256, 6), 256, 0, stream>>>(hb, Wih + 196608, bih + 768,
                                                xp, (float*)0, 32768, 768, 256, 0);
    k_gru<<<32, 512, 0, stream>>>(xp, Whh + 98304, bhh + 768, hb);

    // head: g = bf16(GELU(hb @ W2^T + b2)); d_out = fp32(g @ W3^T + b3)
    k_gemm_bt<<<dim3(256, 2), 256, 0, stream>>>(hb, W2, b2, g, (float*)0,
                                                32768, 256, 256, 1);
    k_gemm_bt<<<dim3(256, 1), 256, 0, stream>>>(g, W3, b3, (ushort*)0,
                                                (float*)d_out, 32768, 50, 256, 0);
}